// Round 9
// baseline (98.134 us; speedup 1.0000x reference)
//
#include <hip/hip_runtime.h>
#include <math.h>

#define BROWS 8192
#define F 10
#define QP 20                   // poolQ row pitch in f16 (40 B), feats 10..19 = 0
#define LOG2E 1.44269504088896340736f

#if __has_builtin(__builtin_amdgcn_exp2f)
#define EXP2F(x) __builtin_amdgcn_exp2f(x)
#else
#define EXP2F(x) exp2f(x)
#endif

typedef _Float16 half4 __attribute__((ext_vector_type(4)));
typedef __fp16 fp16x2 __attribute__((ext_vector_type(2)));
typedef float floatx4 __attribute__((ext_vector_type(4)));

__device__ __forceinline__ half4 exp4_to_h4(float a, float b, float c, float d) {
#if __has_builtin(__builtin_amdgcn_cvt_pkrtz)
    union { fp16x2 h2[2]; half4 h4; } u;
    u.h2[0] = __builtin_amdgcn_cvt_pkrtz(EXP2F(a), EXP2F(b));
    u.h2[1] = __builtin_amdgcn_cvt_pkrtz(EXP2F(c), EXP2F(d));
    return u.h4;
#else
    half4 r;
    r[0] = (_Float16)EXP2F(a); r[1] = (_Float16)EXP2F(b);
    r[2] = (_Float16)EXP2F(c); r[3] = (_Float16)EXP2F(d);
    return r;
#endif
}

__device__ __forceinline__ uint32_t pack2(_Float16 a, _Float16 b) {
    union { _Float16 h[2]; uint32_t u; } x;
    x.h[0] = a; x.h[1] = b;
    return x.u;
}

// ---------------------------------------------------------------------------
// Kernel 1: pooled in TWO f16 layouts.
//   poolQ[b][0..19]: feats 0..9, 10..19 = 0       (row-major, 40 B rows)
//   poolT16[n][b], n = 0..15: rows 0..9 = pooled^T, row 10 = ONES (softmax
//   denominator via MFMA), rows 11..15 = 0.  Direct MFMA2-A operand source.
// ---------------------------------------------------------------------------
__global__ void pooled_kernel(const float* __restrict__ x,
                              const float* __restrict__ A,
                              const float* __restrict__ W,
                              _Float16* __restrict__ poolQ,
                              _Float16* __restrict__ poolT16) {
    int b = blockIdx.x * blockDim.x + threadIdx.x;
    if (b >= BROWS) return;

    float c0 = 0.125f * (1.0f + A[0] + A[3]);
    float c1 = 0.125f * (1.0f + A[1] + A[4]);
    float c2 = 0.125f * (2.0f + A[2] + A[5]);

    const float2* xb = (const float2*)(x + (size_t)b * 3 * F);
    float xv[3 * F];
#pragma unroll
    for (int k = 0; k < 15; ++k) {
        float2 t = xb[k];
        xv[2 * k] = t.x; xv[2 * k + 1] = t.y;
    }

    float y[F];
#pragma unroll
    for (int f = 0; f < F; ++f)
        y[f] = c0 * xv[f] + c1 * xv[F + f] + c2 * xv[2 * F + f];

    float po[F];
#pragma unroll
    for (int o = 0; o < F; ++o) {
        float acc = 0.0f;
#pragma unroll
        for (int f = 0; f < F; ++f)
            acc = fmaf(y[f], W[f * F + o], acc);
        po[o] = acc;
    }

    uint2* qd = (uint2*)(poolQ + (size_t)b * QP);
    qd[0] = make_uint2(pack2((_Float16)po[0], (_Float16)po[1]),
                       pack2((_Float16)po[2], (_Float16)po[3]));
    qd[1] = make_uint2(pack2((_Float16)po[4], (_Float16)po[5]),
                       pack2((_Float16)po[6], (_Float16)po[7]));
    qd[2] = make_uint2(pack2((_Float16)po[8], (_Float16)po[9]), 0u);
    qd[3] = make_uint2(0u, 0u);
    qd[4] = make_uint2(0u, 0u);

#pragma unroll
    for (int o = 0; o < F; ++o)
        poolT16[(size_t)o * BROWS + b] = (_Float16)po[o];   // coalesced over b
    poolT16[(size_t)10 * BROWS + b] = (_Float16)1.0f;       // denominator row
#pragma unroll
    for (int o = 11; o < 16; ++o)
        poolT16[(size_t)o * BROWS + b] = (_Float16)0.0f;
}

// ---------------------------------------------------------------------------
// Kernel 2: MFMA flash attention, NO LDS STAGING, no main-loop barriers.
// poolQ (320 KB) + poolT16 (256 KB) are L2-resident and shared by all 512
// blocks — operand fragments are plain global_load_dwordx2 from L2, software-
// pipelined by the compiler across the unrolled regular stream (R8 showed the
// LDS-staging structure latency/barrier-bound at ~23 us vs ~6 us issue model).
// Block (512 thr = 8 waves) owns i-tile = 16 rows; wave w covers
// j = t*512 + w*64 + c*16 + [0,16).
//   MFMA1 (swapped): D1 = Pj-frag * Pi-frag -> S^T, C-layout == B-layout
//   exp2 -> f16 -> MFMA2: acc += poolT16-frag * expS  (acc = V^T, row10 = l)
// End: 6 KB LDS reduce over the 8 waves, fused normalize.
// ---------------------------------------------------------------------------
__global__ void attn_kernel(const _Float16* __restrict__ poolQ,
                            const _Float16* __restrict__ poolT16,
                            float* __restrict__ out) {
    __shared__ __align__(16) float red[8 * 16 * 12];   // 6144 B total LDS

    const int tid  = threadIdx.x;
    const int wave = tid >> 6;
    const int lane = tid & 63;
    const int m    = lane & 15;
    const int quad = lane >> 4;
    const int irow = blockIdx.x * 16 + m;

    // B1 fragment: B[k=f][n=i] = poolQ[irow][quad*4+idx] * log2(e)
    half4 b1;
#pragma unroll
    for (int idx = 0; idx < 4; ++idx) {
        int f = quad * 4 + idx;
        float v = (f < F) ? (float)poolQ[(size_t)irow * QP + f] * LOG2E : 0.0f;
        b1[idx] = (_Float16)v;
    }

    // per-lane base pointers; loop advances by constant byte strides
    const char* qbase = (const char*)poolQ
                      + (size_t)(wave * 64 + m) * (QP * 2) + quad * 8;
    const char* tbase = (const char*)poolT16
                      + (size_t)m * (BROWS * 2) + (size_t)(wave * 64) * 2 + quad * 8;

    floatx4 acc0 = {0.f, 0.f, 0.f, 0.f};
    floatx4 acc1 = {0.f, 0.f, 0.f, 0.f};

    // 64 iterations: idx -> t = idx>>2 (512-j stride), c = idx&3 (16-j stride)
#pragma unroll 8
    for (int idx = 0; idx < 64; ++idx) {
        const int t = idx >> 2, c = idx & 3;
        const int joff = t * 512 + c * 16;            // j offset within wave slice
        half4 a1 = *(const half4*)(qbase + (size_t)joff * (QP * 2));
        half4 ag = *(const half4*)(tbase + (size_t)joff * 2);
        floatx4 d1 = __builtin_amdgcn_mfma_f32_16x16x16f16(
            a1, b1, (floatx4){0.f, 0.f, 0.f, 0.f}, 0, 0, 0);
        half4 a2 = exp4_to_h4(d1[0], d1[1], d1[2], d1[3]);
        if (idx & 1)
            acc1 = __builtin_amdgcn_mfma_f32_16x16x16f16(ag, a2, acc1, 0, 0, 0);
        else
            acc0 = __builtin_amdgcn_mfma_f32_16x16x16f16(ag, a2, acc0, 0, 0, 0);
    }

    floatx4 acc = acc0 + acc1;   // lane: V^T[f=quad*4+r][i=m], f=10 -> l

    if (quad < 3)
        *(floatx4*)&red[(wave * 16 + m) * 12 + quad * 4] = acc;
    __syncthreads();

    if (tid < 160) {
        const int i16 = tid / 10;
        const int f   = tid % 10;
        float sum = 0.0f, l = 0.0f;
#pragma unroll
        for (int w = 0; w < 8; ++w) {
            sum += red[(w * 16 + i16) * 12 + f];
            l   += red[(w * 16 + i16) * 12 + 10];
        }
        out[(size_t)(blockIdx.x * 16 + i16) * F + f] = sum / l;
    }
}

// ---------------------------------------------------------------------------
extern "C" void kernel_launch(void* const* d_in, const int* in_sizes, int n_in,
                              void* d_out, int out_size, void* d_ws, size_t ws_size,
                              hipStream_t stream) {
    const float* x = (const float*)d_in[0];   // [8192,3,10]
    const float* A = (const float*)d_in[1];   // [3,3]
    const float* W = (const float*)d_in[2];   // [10,10]
    float* out = (float*)d_out;               // [8192,10]

    _Float16* poolQ   = (_Float16*)d_ws;                      // 8192*20*2 = 327680 B
    _Float16* poolT16 = (_Float16*)((char*)d_ws + 327680);    // 16*8192*2 = 262144 B

    pooled_kernel<<<BROWS / 64, 64, 0, stream>>>(x, A, W, poolQ, poolT16);
    attn_kernel<<<BROWS / 16, 512, 0, stream>>>(poolQ, poolT16, out);
}

// Round 10
// 75.500 us; speedup vs baseline: 1.2998x; 1.2998x over previous
//
#include <hip/hip_runtime.h>
#include <math.h>

#define BROWS 8192
#define F 10
#define TJ 512                  // j-rows staged per round
#define QP 20                   // poolQ/qbuf row pitch in f16 (40 B)
#define AP 524                  // abuf row pitch in f16 (262 dw; 262%32=6 -> balanced banks)
#define NT (BROWS / TJ)         // 16 tiles
#define LOG2E 1.44269504088896340736f

#if __has_builtin(__builtin_amdgcn_exp2f)
#define EXP2F(x) __builtin_amdgcn_exp2f(x)
#else
#define EXP2F(x) exp2f(x)
#endif

typedef _Float16 half4 __attribute__((ext_vector_type(4)));
typedef __fp16 fp16x2 __attribute__((ext_vector_type(2)));
typedef float floatx4 __attribute__((ext_vector_type(4)));

__device__ __forceinline__ half4 exp4_to_h4(float a, float b, float c, float d) {
#if __has_builtin(__builtin_amdgcn_cvt_pkrtz)
    union { fp16x2 h2[2]; half4 h4; } u;
    u.h2[0] = __builtin_amdgcn_cvt_pkrtz(EXP2F(a), EXP2F(b));
    u.h2[1] = __builtin_amdgcn_cvt_pkrtz(EXP2F(c), EXP2F(d));
    return u.h4;
#else
    half4 r;
    r[0] = (_Float16)EXP2F(a); r[1] = (_Float16)EXP2F(b);
    r[2] = (_Float16)EXP2F(c); r[3] = (_Float16)EXP2F(d);
    return r;
#endif
}

__device__ __forceinline__ uint32_t pack2(_Float16 a, _Float16 b) {
    union { _Float16 h[2]; uint32_t u; } x;
    x.h[0] = a; x.h[1] = b;
    return x.u;
}

// async global->LDS DMA, 16B/lane; lds addr = wave-uniform base + lane*16.
__device__ __forceinline__ void gload_lds16(const void* g, void* l) {
#if __has_builtin(__builtin_amdgcn_global_load_lds)
    __builtin_amdgcn_global_load_lds(
        (const __attribute__((address_space(1))) void*)g,
        (__attribute__((address_space(3))) void*)l, 16, 0, 0);
#else
    *(float4*)l = *(const float4*)g;
#endif
}

// ---------------------------------------------------------------------------
// Kernel 1: pooled in TWO f16 layouts.
//   poolQ[b][0..19]: feats 0..9, 10..19 = 0       (row-major, 40 B rows)
//   poolT16[n][b], n = 0..15: rows 0..9 = pooled^T, row 10 = ONES (softmax
//   denominator via MFMA), rows 11..15 = 0.  DMA'd whole into abuf each tile.
// ---------------------------------------------------------------------------
__global__ void pooled_kernel(const float* __restrict__ x,
                              const float* __restrict__ A,
                              const float* __restrict__ W,
                              _Float16* __restrict__ poolQ,
                              _Float16* __restrict__ poolT16) {
    int b = blockIdx.x * blockDim.x + threadIdx.x;
    if (b >= BROWS) return;

    float c0 = 0.125f * (1.0f + A[0] + A[3]);
    float c1 = 0.125f * (1.0f + A[1] + A[4]);
    float c2 = 0.125f * (2.0f + A[2] + A[5]);

    const float2* xb = (const float2*)(x + (size_t)b * 3 * F);
    float xv[3 * F];
#pragma unroll
    for (int k = 0; k < 15; ++k) {
        float2 t = xb[k];
        xv[2 * k] = t.x; xv[2 * k + 1] = t.y;
    }

    float y[F];
#pragma unroll
    for (int f = 0; f < F; ++f)
        y[f] = c0 * xv[f] + c1 * xv[F + f] + c2 * xv[2 * F + f];

    float po[F];
#pragma unroll
    for (int o = 0; o < F; ++o) {
        float acc = 0.0f;
#pragma unroll
        for (int f = 0; f < F; ++f)
            acc = fmaf(y[f], W[f * F + o], acc);
        po[o] = acc;
    }

    uint2* qd = (uint2*)(poolQ + (size_t)b * QP);
    qd[0] = make_uint2(pack2((_Float16)po[0], (_Float16)po[1]),
                       pack2((_Float16)po[2], (_Float16)po[3]));
    qd[1] = make_uint2(pack2((_Float16)po[4], (_Float16)po[5]),
                       pack2((_Float16)po[6], (_Float16)po[7]));
    qd[2] = make_uint2(pack2((_Float16)po[8], (_Float16)po[9]), 0u);
    qd[3] = make_uint2(0u, 0u);
    qd[4] = make_uint2(0u, 0u);

#pragma unroll
    for (int o = 0; o < F; ++o)
        poolT16[(size_t)o * BROWS + b] = (_Float16)po[o];   // coalesced over b
    poolT16[(size_t)10 * BROWS + b] = (_Float16)1.0f;       // denominator row
#pragma unroll
    for (int o = 11; o < 16; ++o)
        poolT16[(size_t)o * BROWS + b] = (_Float16)0.0f;
}

// ---------------------------------------------------------------------------
// Kernel 2: MFMA flash attention, DMA-staged, double-buffered, 1 barrier/tile.
// R10 fix: LDS 80.4 KB -> 74.5 KB (red aliased into qbuf[0], const rows DMA'd
// from poolT16) => 2 blocks/CU, 4 waves/SIMD — R8's 1-block/CU occupancy was
// the 23-vs-6 us gap (2 waves/SIMD couldn't hide ds_read->MFMA->exp chains).
// Block (512 thr = 8 waves) owns i-tile = 16 rows; wave w covers its 64-j
// slice of each staged 512-j tile.
//   MFMA1 (swapped): D1 = Pj-frag * Pi-frag -> S^T, C-layout == B-layout
//   exp2 -> f16 -> MFMA2: acc += abuf-frag * expS  (acc = V^T, row 10 = l)
// ---------------------------------------------------------------------------
__global__ void attn_kernel(const _Float16* __restrict__ poolQ,
                            const _Float16* __restrict__ poolT16,
                            float* __restrict__ out) {
    __shared__ __align__(16) _Float16 qbuf[2][TJ * QP];   // 2 x 20480 B
    __shared__ __align__(16) _Float16 abuf[2][16 * AP];   // 2 x 16768 B
    float* red = (float*)&qbuf[0][0];   // aliased: used only after final barrier

    const int tid  = threadIdx.x;
    const int wave = tid >> 6;
    const int lane = tid & 63;
    const int m    = lane & 15;
    const int quad = lane >> 4;
    const int irow = blockIdx.x * 16 + m;

    // B1 fragment: B[k=f][n=i] = poolQ[irow][quad*4+idx] * log2(e)
    half4 b1;
#pragma unroll
    for (int idx = 0; idx < 4; ++idx) {
        int f = quad * 4 + idx;
        float v = (f < F) ? (float)poolQ[(size_t)irow * QP + f] * LOG2E : 0.0f;
        b1[idx] = (_Float16)v;
    }

    // DMA one tile (wave-cooperative: 20 qbuf chunks + 16 abuf rows)
    auto dma_tile = [&](int t, int bufi) {
        const char* qs = (const char*)poolQ + (size_t)t * TJ * QP * 2;  // 20480 B
        char* qd = (char*)&qbuf[bufi][0];
        for (int d = wave; d < 20; d += 8)
            gload_lds16(qs + d * 1024 + lane * 16, qd + d * 1024 + lane * 16);
        char* ad = (char*)&abuf[bufi][0];
        for (int n = wave; n < 16; n += 8)
            gload_lds16((const char*)(poolT16 + (size_t)n * BROWS + t * TJ) + lane * 16,
                        ad + n * (AP * 2) + lane * 16);
    };

    floatx4 acc0 = {0.f, 0.f, 0.f, 0.f};
    floatx4 acc1 = {0.f, 0.f, 0.f, 0.f};

    dma_tile(0, 0);
    __syncthreads();   // drains tile-0 DMA

    for (int t = 0; t < NT; ++t) {
        const int buf = t & 1;
        if (t + 1 < NT) dma_tile(t + 1, buf ^ 1);   // flies during compute

#pragma unroll
        for (int c = 0; c < 4; ++c) {
            const int jb = wave * 64 + c * 16;
            half4 ag = *(const half4*)&abuf[buf][m * AP + jb + quad * 4];
            half4 a1 = *(const half4*)&qbuf[buf][(jb + m) * QP + quad * 4];
            floatx4 d1 = __builtin_amdgcn_mfma_f32_16x16x16f16(
                a1, b1, (floatx4){0.f, 0.f, 0.f, 0.f}, 0, 0, 0);
            half4 a2 = exp4_to_h4(d1[0], d1[1], d1[2], d1[3]);
            if (c & 1)
                acc1 = __builtin_amdgcn_mfma_f32_16x16x16f16(ag, a2, acc1, 0, 0, 0);
            else
                acc0 = __builtin_amdgcn_mfma_f32_16x16x16f16(ag, a2, acc0, 0, 0, 0);
        }
        __syncthreads();   // one barrier/tile: drains t+1 DMAs, releases buf
    }

    floatx4 acc = acc0 + acc1;   // lane: V^T[f=quad*4+r][i=m], f=10 -> l

    // reduce over the 8 waves (red aliases qbuf[0]; all compute is barriered out)
    if (quad < 3)
        *(floatx4*)&red[(wave * 16 + m) * 12 + quad * 4] = acc;
    __syncthreads();

    if (tid < 160) {
        const int i16 = tid / 10;
        const int f   = tid % 10;
        float sum = 0.0f, l = 0.0f;
#pragma unroll
        for (int w = 0; w < 8; ++w) {
            sum += red[(w * 16 + i16) * 12 + f];
            l   += red[(w * 16 + i16) * 12 + 10];
        }
        out[(size_t)(blockIdx.x * 16 + i16) * F + f] = sum / l;
    }
}

// ---------------------------------------------------------------------------
extern "C" void kernel_launch(void* const* d_in, const int* in_sizes, int n_in,
                              void* d_out, int out_size, void* d_ws, size_t ws_size,
                              hipStream_t stream) {
    const float* x = (const float*)d_in[0];   // [8192,3,10]
    const float* A = (const float*)d_in[1];   // [3,3]
    const float* W = (const float*)d_in[2];   // [10,10]
    float* out = (float*)d_out;               // [8192,10]

    _Float16* poolQ   = (_Float16*)d_ws;                      // 8192*20*2 = 327680 B
    _Float16* poolT16 = (_Float16*)((char*)d_ws + 327680);    // 16*8192*2 = 262144 B

    pooled_kernel<<<BROWS / 64, 64, 0, stream>>>(x, A, W, poolQ, poolT16);
    attn_kernel<<<BROWS / 16, 512, 0, stream>>>(poolQ, poolT16, out);
}